// Round 1
// baseline (927.665 us; speedup 1.0000x reference)
//
#include <hip/hip_runtime.h>

// LocalGridAlignAttention: B=8, C=256, H=W=64, HF=WF=256, HEADS=8, hd=32, rh=rw=4
// Restructured: energy = (q^T wk_head) . f  -> avoids 68.7 GFLOP K-projection.

namespace {

constexpr float SCALE = 0.17677669529663687f; // 32^-0.5
constexpr int PX = 16; // query pixels per block (w-strip)

// wqT[c][oc] = wq[oc][c] * SCALE   (256x256)
__global__ void transpose_scale_k(const float* __restrict__ wq, float* __restrict__ wqT) {
  __shared__ float tile[32][33];
  const int tx = threadIdx.x & 31, ty = threadIdx.x >> 5; // 32 x 8
  const int ocb = blockIdx.x * 32, cb = blockIdx.y * 32;
#pragma unroll
  for (int j = 0; j < 32; j += 8)
    tile[ty + j][tx] = wq[(ocb + ty + j) * 256 + cb + tx];
  __syncthreads();
#pragma unroll
  for (int j = 0; j < 32; j += 8)
    wqT[(cb + ty + j) * 256 + ocb + tx] = tile[tx][ty + j] * SCALE;
}

__global__ __launch_bounds__(256) void attn_fused_k(
    const float* __restrict__ x, const float* __restrict__ fm,
    const float* __restrict__ wqT, const float* __restrict__ bq,
    const float* __restrict__ wk, const float* __restrict__ bk,
    float* __restrict__ out) {
  // LDS: 12288 floats = 48 KB -> 3 blocks/CU
  __shared__ float sm[12288];
  float* const qs    = sm;          // [16][256] q values (scaled, biased)
  float* const xs    = sm + 4096;   // [256][16] x slice (dead after phase 1)
  float* const es    = sm + 4096;   // [16][164] energies/attn (px*164 + head*20 + pos)
  float* const ebias = sm + 6720;   // [16][8]   q.bk bias term
  float* const wqc   = sm + 8192;   // [16][256] wqT chunk (phase 1)
  float* const qws   = sm + 8192;   // [32][16][8] qw chunk, slot-swizzled (phase 2)

  const int t = threadIdx.x;
  const int bid = blockIdx.x;
  const int b  = bid >> 8;          // 8 batches
  const int h  = (bid >> 2) & 63;   // 64 rows
  const int w0 = (bid & 3) * PX;    // 4 strips of 16

  // ---------- Phase 0: stage x slice: xs[c][px] ----------
  {
    const float* xp = x + (size_t)(b * 256) * 4096 + h * 64 + w0;
#pragma unroll
    for (int j = 0; j < 16; ++j) {
      const int idx = j * 256 + t;
      const int c = idx >> 4, px = idx & 15;
      xs[c * 16 + px] = xp[c * 4096 + px];
    }
  }
  __syncthreads();

  // ---------- Phase 1: q = x @ (wq^T * s) + bq*s ----------
  {
    const int ocb = (t & 63) * 4;  // 4 out channels
    const int pxb = (t >> 6) * 4;  // 4 px (wave-uniform)
    float acc[4][4] = {};
    for (int cb = 0; cb < 256; cb += 16) {
      if (cb) __syncthreads();
#pragma unroll
      for (int j = 0; j < 4; ++j) {
        const int idx = j * 1024 + t * 4;
        *(float4*)&wqc[idx] = *(const float4*)&wqT[cb * 256 + idx];
      }
      __syncthreads();
#pragma unroll
      for (int c = 0; c < 16; ++c) {
        const float4 xv = *(const float4*)&xs[(cb + c) * 16 + pxb];
        const float4 wv = *(const float4*)&wqc[c * 256 + ocb];
        const float xa[4] = {xv.x, xv.y, xv.z, xv.w};
        const float wa[4] = {wv.x, wv.y, wv.z, wv.w};
#pragma unroll
        for (int j = 0; j < 4; ++j)
#pragma unroll
          for (int i = 0; i < 4; ++i) acc[j][i] += xa[j] * wa[i];
      }
    }
    const float4 bqv = *(const float4*)&bq[ocb];
    const float ba[4] = {bqv.x * SCALE, bqv.y * SCALE, bqv.z * SCALE, bqv.w * SCALE};
#pragma unroll
    for (int j = 0; j < 4; ++j) {
      float4 qv;
      qv.x = acc[j][0] + ba[0]; qv.y = acc[j][1] + ba[1];
      qv.z = acc[j][2] + ba[2]; qv.w = acc[j][3] + ba[3];
      *(float4*)&qs[(pxb + j) * 256 + ocb] = qv;
    }
  }
  __syncthreads();

  // ---------- energy bias: ebias[px][head] = q . bk ----------
  if (t < 128) {
    const int px = t >> 3, head = t & 7;
    const float* qp = &qs[px * 256 + head * 32];
    const float* bp = &bk[head * 32];
    float s = 0.f;
#pragma unroll
    for (int c = 0; c < 32; c += 4) {
      const float4 qv = *(const float4*)&qp[c];
      const float4 bv = *(const float4*)&bp[c];
      s += qv.x * bv.x + qv.y * bv.y + qv.z * bv.z + qv.w * bv.w;
    }
    ebias[px * 8 + head] = s;
  }
  // (uses of ebias are separated by multiple barriers below)

  // ---------- Phase 2: qw fold + energy, chunks of 32 channels ----------
  float e[8] = {0.f, 0.f, 0.f, 0.f, 0.f, 0.f, 0.f, 0.f};
  const int hf_off = t >> 6;        // window row 0..3 (wave-uniform)
  const int wf_off = t & 63;        // window col 0..63
  const int px2 = wf_off >> 2;      // query pixel 0..15
  const int posq = wf_off & 3;      // window sub-col 0..3
  const int head2a = t >> 5;        // 0..7
  const int Cc2a = t & 31;          // 0..31

  for (int C0 = 0; C0 < 256; C0 += 32) {
    // 2a: qws[Cc][px][head] = sum_{c'} qs[px][head*32+c'] * wk[head*32+c'][C0+Cc]
    float qacc[16] = {};
    {
      const float* wkp = wk + (size_t)(head2a * 32) * 256 + C0 + Cc2a;
#pragma unroll
      for (int c4 = 0; c4 < 8; ++c4) {
        const float wv0 = wkp[(c4 * 4 + 0) * 256];
        const float wv1 = wkp[(c4 * 4 + 1) * 256];
        const float wv2 = wkp[(c4 * 4 + 2) * 256];
        const float wv3 = wkp[(c4 * 4 + 3) * 256];
#pragma unroll
        for (int px = 0; px < 16; ++px) {
          const float4 qv = *(const float4*)&qs[px * 256 + head2a * 32 + c4 * 4];
          qacc[px] += qv.x * wv0 + qv.y * wv1 + qv.z * wv2 + qv.w * wv3;
        }
      }
    }
    __syncthreads();  // previous 2b reads of qws done
#pragma unroll
    for (int px = 0; px < 16; ++px)
      qws[(Cc2a * 16 + (px ^ (Cc2a & 15))) * 8 + head2a] = qacc[px];
    __syncthreads();
    // 2b: energy accumulate; thread owns one window pixel of the 4x64 strip
    {
      const float* fp = fm + ((size_t)(b * 256 + C0) * 256 + (4 * h + hf_off)) * 256
                        + 4 * w0 + wf_off;
#pragma unroll 8
      for (int Cc = 0; Cc < 32; ++Cc) {
        const float fv = fp[(size_t)Cc * 65536];
        const int base = (Cc * 16 + (px2 ^ (Cc & 15))) * 8;
        const float4 a0 = *(const float4*)&qws[base];
        const float4 a1 = *(const float4*)&qws[base + 4];
        e[0] += fv * a0.x; e[1] += fv * a0.y; e[2] += fv * a0.z; e[3] += fv * a0.w;
        e[4] += fv * a1.x; e[5] += fv * a1.y; e[6] += fv * a1.z; e[7] += fv * a1.w;
      }
    }
  }

  // write energies (+ bias) to es[px][head][pos]  (xs is dead)
  {
    const int pos = hf_off * 4 + posq;
#pragma unroll
    for (int head = 0; head < 8; ++head)
      es[px2 * 164 + head * 20 + pos] = e[head] + ebias[px2 * 8 + head];
  }
  __syncthreads();

  // ---------- Phase 3: softmax over 16 positions ----------
  if (t < 128) {
    const int px = t >> 3, head = t & 7;
    float* ep = &es[px * 164 + head * 20];
    float4 v0 = ((float4*)ep)[0];
    float4 v1 = ((float4*)ep)[1];
    float4 v2 = ((float4*)ep)[2];
    float4 v3 = ((float4*)ep)[3];
    const float m =
        fmaxf(fmaxf(fmaxf(fmaxf(v0.x, v0.y), fmaxf(v0.z, v0.w)),
                    fmaxf(fmaxf(v1.x, v1.y), fmaxf(v1.z, v1.w))),
              fmaxf(fmaxf(fmaxf(v2.x, v2.y), fmaxf(v2.z, v2.w)),
                    fmaxf(fmaxf(v3.x, v3.y), fmaxf(v3.z, v3.w))));
    v0.x = __expf(v0.x - m); v0.y = __expf(v0.y - m);
    v0.z = __expf(v0.z - m); v0.w = __expf(v0.w - m);
    v1.x = __expf(v1.x - m); v1.y = __expf(v1.y - m);
    v1.z = __expf(v1.z - m); v1.w = __expf(v1.w - m);
    v2.x = __expf(v2.x - m); v2.y = __expf(v2.y - m);
    v2.z = __expf(v2.z - m); v2.w = __expf(v2.w - m);
    v3.x = __expf(v3.x - m); v3.y = __expf(v3.y - m);
    v3.z = __expf(v3.z - m); v3.w = __expf(v3.w - m);
    const float ssum = (v0.x + v0.y + v0.z + v0.w) + (v1.x + v1.y + v1.z + v1.w)
                     + (v2.x + v2.y + v2.z + v2.w) + (v3.x + v3.y + v3.z + v3.w);
    const float inv = 1.0f / ssum;
    v0.x *= inv; v0.y *= inv; v0.z *= inv; v0.w *= inv;
    v1.x *= inv; v1.y *= inv; v1.z *= inv; v1.w *= inv;
    v2.x *= inv; v2.y *= inv; v2.z *= inv; v2.w *= inv;
    v3.x *= inv; v3.y *= inv; v3.z *= inv; v3.w *= inv;
    ((float4*)ep)[0] = v0; ((float4*)ep)[1] = v1;
    ((float4*)ep)[2] = v2; ((float4*)ep)[3] = v3;
  }
  __syncthreads();

  // ---------- Phase 4: out[oc][px] = sum_pos attn * fm[oc, window pos] ----------
  {
    const int px = t & 15, ocg = t >> 4;  // 16 px x 16 oc-groups
#pragma unroll
    for (int head = 0; head < 8; ++head) {
      const float* ap = &es[px * 164 + head * 20];
      const float4 a0 = ((const float4*)ap)[0];
      const float4 a1 = ((const float4*)ap)[1];
      const float4 a2 = ((const float4*)ap)[2];
      const float4 a3 = ((const float4*)ap)[3];
#pragma unroll
      for (int jj = 0; jj < 2; ++jj) {
        const int oc = head * 32 + jj * 16 + ocg;
        const float* fp = fm + ((size_t)(b * 256 + oc) * 256 + 4 * h) * 256
                          + 4 * (w0 + px);
        const float4 f0 = *(const float4*)&fp[0];
        const float4 f1 = *(const float4*)&fp[256];
        const float4 f2 = *(const float4*)&fp[512];
        const float4 f3 = *(const float4*)&fp[768];
        const float o = a0.x * f0.x + a0.y * f0.y + a0.z * f0.z + a0.w * f0.w
                      + a1.x * f1.x + a1.y * f1.y + a1.z * f1.z + a1.w * f1.w
                      + a2.x * f2.x + a2.y * f2.y + a2.z * f2.z + a2.w * f2.w
                      + a3.x * f3.x + a3.y * f3.y + a3.z * f3.z + a3.w * f3.w;
        out[(size_t)(b * 256 + oc) * 4096 + h * 64 + w0 + px] = o;
      }
    }
  }
}

} // namespace

extern "C" void kernel_launch(void* const* d_in, const int* in_sizes, int n_in,
                              void* d_out, int out_size, void* d_ws, size_t ws_size,
                              hipStream_t stream) {
  const float* x  = (const float*)d_in[0];
  const float* fm = (const float*)d_in[1];
  const float* wq = (const float*)d_in[2];
  const float* bq = (const float*)d_in[3];
  const float* wk = (const float*)d_in[4];
  const float* bk = (const float*)d_in[5];
  float* out = (float*)d_out;
  float* wqT = (float*)d_ws;  // 256 KB scratch

  transpose_scale_k<<<dim3(8, 8), 256, 0, stream>>>(wq, wqT);
  attn_fused_k<<<2048, 256, 0, stream>>>(x, fm, wqT, bq, wk, bk, out);
}